// Round 3
// baseline (3483.752 us; speedup 1.0000x reference)
//
#include <hip/hip_runtime.h>
#include <hip/hip_bf16.h>
#include <math.h>

// RSM: M=1000 columns, N=4 cells/col, K=25 winners, T=64, B=128, D_IN=1024, D_OUT=1024
#define MCOL   1000
#define NCELL  4
#define TCELL  4000
#define KWIN   25
#define TT     64
#define BB     128
#define DIN    1024
#define DOUT   1024

// ---------------------------------------------------------------------------
// Generic fp32 transpose: src[R][C] -> dst[C][R]
// ---------------------------------------------------------------------------
__global__ void transpose_k(const float* __restrict__ src, float* __restrict__ dst,
                            int R, int C) {
    __shared__ float tile[32][33];
    int c0 = blockIdx.x * 32, r0 = blockIdx.y * 32;
    int tx = threadIdx.x, ty = threadIdx.y;
#pragma unroll
    for (int q = 0; q < 4; ++q) {
        int r = r0 + ty + q * 8, c = c0 + tx;
        tile[ty + q * 8][tx] = (r < R && c < C) ? src[(size_t)r * C + c] : 0.f;
    }
    __syncthreads();
#pragma unroll
    for (int q = 0; q < 4; ++q) {
        int c = c0 + ty + q * 8, r = r0 + tx;
        if (c < C && r < R) dst[(size_t)c * R + r] = tile[tx][ty + q * 8];
    }
}

// ---------------------------------------------------------------------------
// ZA = X[8192,1024] @ w_a^T  -> [8192, 1000]   (fp32 vector GEMM, 128x128x16)
// ---------------------------------------------------------------------------
__launch_bounds__(256, 2)
__global__ void za_gemm(const float* __restrict__ A,   // [8192,1024]
                        const float* __restrict__ Bw,  // [1000,1024]
                        float* __restrict__ C) {       // [8192,1000]
    __shared__ float As[16][132];
    __shared__ float Bs[16][132];
    const int i0 = blockIdx.x * 128;
    const int m0 = blockIdx.y * 128;
    const int tid = threadIdx.x;
    const int tx = tid & 15, ty = tid >> 4;
    float acc[8][8];
#pragma unroll
    for (int a = 0; a < 8; ++a)
#pragma unroll
        for (int b = 0; b < 8; ++b) acc[a][b] = 0.f;

    for (int k0 = 0; k0 < DIN; k0 += 16) {
#pragma unroll
        for (int p = 0; p < 2; ++p) {
            int f = tid + p * 256;          // 0..511 float4 slots
            int row = f >> 2, c4 = (f & 3) * 4;
            float4 v = *reinterpret_cast<const float4*>(
                &A[(size_t)(i0 + row) * DIN + k0 + c4]);
            As[c4 + 0][row] = v.x; As[c4 + 1][row] = v.y;
            As[c4 + 2][row] = v.z; As[c4 + 3][row] = v.w;
            int m = m0 + row;
            float4 w = make_float4(0.f, 0.f, 0.f, 0.f);
            if (m < MCOL)
                w = *reinterpret_cast<const float4*>(&Bw[(size_t)m * DIN + k0 + c4]);
            Bs[c4 + 0][row] = w.x; Bs[c4 + 1][row] = w.y;
            Bs[c4 + 2][row] = w.z; Bs[c4 + 3][row] = w.w;
        }
        __syncthreads();
#pragma unroll
        for (int kk = 0; kk < 16; ++kk) {
            float4 a0 = *reinterpret_cast<const float4*>(&As[kk][ty * 8]);
            float4 a1 = *reinterpret_cast<const float4*>(&As[kk][ty * 8 + 4]);
            float4 b0 = *reinterpret_cast<const float4*>(&Bs[kk][tx * 8]);
            float4 b1 = *reinterpret_cast<const float4*>(&Bs[kk][tx * 8 + 4]);
            float av[8] = {a0.x, a0.y, a0.z, a0.w, a1.x, a1.y, a1.z, a1.w};
            float bv[8] = {b0.x, b0.y, b0.z, b0.w, b1.x, b1.y, b1.z, b1.w};
#pragma unroll
            for (int ii = 0; ii < 8; ++ii)
#pragma unroll
                for (int jj = 0; jj < 8; ++jj)
                    acc[ii][jj] = fmaf(av[ii], bv[jj], acc[ii][jj]);
        }
        __syncthreads();
    }
#pragma unroll
    for (int ii = 0; ii < 8; ++ii) {
        int i = i0 + ty * 8 + ii;
#pragma unroll
        for (int jj = 0; jj < 8; ++jj) {
            int m = m0 + tx * 8 + jj;
            if (m < MCOL) C[(size_t)i * MCOL + m] = acc[ii][jj];
        }
    }
}

__device__ __forceinline__ unsigned long long shflxor64(unsigned long long v, int m) {
    int lo = __shfl_xor((int)(unsigned int)(v & 0xffffffffull), m);
    int hi = __shfl_xor((int)(unsigned int)(v >> 32), m);
    return ((unsigned long long)(unsigned int)hi << 32) | (unsigned int)lo;
}

// ---------------------------------------------------------------------------
// Persistent recurrence kernel: 1 WG (512 threads, 8 waves) per batch row.
// Thread t owns columns t and t+512 (latter if t<488).
// __launch_bounds__(512, 1): 1 block/CU -> 2 waves/SIMD -> 256-VGPR budget,
// so the 26x float4 + 50x float gather batch stays in registers (no scratch).
// Top-25 selection: exact single-wave 25x butterfly-max extraction over
// unique u64 keys ((monokey<<10)|(1023-col)) == jax order (val desc, idx asc).
// ---------------------------------------------------------------------------
__launch_bounds__(512, 1)
__global__ void rsm_kernel(const float* __restrict__ ZA,   // [T*B, 1000]
                           const float* __restrict__ wbT,  // [4000,4000] = w_b^T
                           const float* __restrict__ wdT,  // [1000,1024] = w_d^T
                           const float* __restrict__ bd,   // [1024]
                           float* __restrict__ out) {      // [T*B, 1024]
    const int b = blockIdx.x;
    const int tid = threadIdx.x;
    const int lane = tid & 63, wid = tid >> 6;      // 8 waves
    const bool hasB = (tid < (MCOL - 512));         // 488 threads own a 2nd column
    const int c0 = tid, c1 = tid + 512;

    __shared__ unsigned int keyS[1024];
    __shared__ int   argnS[1024];
    __shared__ float dS[1024];
    __shared__ float ycS[1024];
    __shared__ int   flagS[1024];
    __shared__ int   wcellS[KWIN];
    __shared__ float wdS[KWIN];
    __shared__ float wyS[KWIN];

    float Za[4] = {0,0,0,0}, Zb[4] = {0,0,0,0};
    float pha[4] = {0,0,0,0}, phb[4] = {0,0,0,0};
    float psa[4] = {0,0,0,0}, psb[4] = {0,0,0,0};
    const float breg0 = bd[tid], breg1 = bd[tid + 512];

    float za0 = ZA[(size_t)b * MCOL + c0];
    float za1 = hasB ? ZA[(size_t)b * MCOL + c1] : 0.f;

    for (int t = 0; t < TT; ++t) {
        // ---- phase 1: sigma / pi / per-column max+argmax (first-max) ----
        float sig0[4], sig1[4];
        float lam0 = -INFINITY, lam1 = -INFINITY;
        int an0 = 0, an1 = 0;
#pragma unroll
        for (int n = 0; n < 4; ++n) {
            sig0[n] = za0 + Za[n];
            float p0 = sig0[n] * (1.0f - pha[n]);
            if (p0 > lam0) { lam0 = p0; an0 = n; }
            sig1[n] = za1 + Zb[n];
            float p1 = sig1[n] * (1.0f - phb[n]);
            if (p1 > lam1) { lam1 = p1; an1 = n; }
        }
        // speculative winner fields (parallel; selection only picks columns)
        float ysp0 = tanhf(sig0[an0]);
        float ysp1 = tanhf(sig1[an1]);
        {
            unsigned int ub = __float_as_uint(lam0);
            keyS[c0]  = (ub & 0x80000000u) ? ~ub : (ub | 0x80000000u);
            argnS[c0] = an0;
            float pd = 0.5f * psa[an0];
            dS[c0]  = fmaxf(pd, ysp0) - pd;
            ycS[c0] = fmaxf(ysp0, 0.f);
        }
        if (hasB) {
            unsigned int ub = __float_as_uint(lam1);
            keyS[c1]  = (ub & 0x80000000u) ? ~ub : (ub | 0x80000000u);
            argnS[c1] = an1;
            float pd = 0.5f * psb[an1];
            dS[c1]  = fmaxf(pd, ysp1) - pd;
            ycS[c1] = fmaxf(ysp1, 0.f);
        }
        __syncthreads();                                             // B1

        // ---- wave0: exact top-25 extraction ----
        if (wid == 0) {
#pragma unroll
            for (int j = 0; j < 16; ++j) flagS[lane + 64 * j] = 0;
            unsigned long long k[16];
#pragma unroll
            for (int j = 0; j < 16; ++j) {
                int c = lane + 64 * j;
                unsigned int u = (c < MCOL) ? keyS[c] : 0u;   // fakes: tiny keys
                k[j] = ((unsigned long long)u << 10) | (unsigned long long)(1023 - c);
            }
            unsigned long long m = k[0]; int mj = 0;
#pragma unroll
            for (int j = 1; j < 16; ++j) if (k[j] > m) { m = k[j]; mj = j; }
            for (int i = 0; i < KWIN; ++i) {
                unsigned long long g = m;
                for (int d = 32; d; d >>= 1) {
                    unsigned long long o = shflxor64(g, d);
                    if (o > g) g = o;
                }
                if (m == g) {        // unique keys -> exactly one winner lane
                    int c = 1023 - (int)(g & 1023ull);
                    flagS[c]  = 1;
                    wcellS[i] = c * 4 + argnS[c];
                    wdS[i]    = dS[c];
                    wyS[i]    = ycS[c];
                    k[mj] = 0ull;
                    m = k[0]; mj = 0;
#pragma unroll
                    for (int j = 1; j < 16; ++j) if (k[j] > m) { m = k[j]; mj = j; }
                }
            }
        }
        __syncthreads();                                             // B2

        // ---- prefetch next-step feedforward drive (overlaps gathers) ----
        float zan0 = 0.f, zan1 = 0.f;
        if (t + 1 < TT) {
            const float* zr = ZA + (size_t)((t + 1) * BB + b) * MCOL;
            zan0 = zr[c0];
            if (hasB) zan1 = zr[c1];
        }

        // ---- trace updates (registers only) ----
        float y0 = flagS[c0] ? ysp0 : 0.f;
        float y1 = (hasB && flagS[c1]) ? ysp1 : 0.f;
#pragma unroll
        for (int n = 0; n < 4; ++n) {
            float yn0 = (n == an0) ? y0 : 0.f;
            psa[n] = fmaxf(0.5f * psa[n], yn0);     // EPS   = 0.5
            pha[n] = fmaxf(0.5f * pha[n], yn0);     // GAMMA = 0.5
            Za[n] *= 0.5f;                          // exact Z decay
            float yn1 = (n == an1) ? y1 : 0.f;
            psb[n] = fmaxf(0.5f * psb[n], yn1);
            phb[n] = fmaxf(0.5f * phb[n], yn1);
            Zb[n] *= 0.5f;
        }

        // ---- gathers: rank-25 Z update + sparse decode, batched for ILP ----
        float4 ga0[13], gb0[13]; float wd0[13];
#pragma unroll
        for (int j = 0; j < 13; ++j) {
            int cell = wcellS[j];
            wd0[j] = wdS[j];
            const float* p = wbT + (size_t)cell * TCELL;
            ga0[j] = *reinterpret_cast<const float4*>(p + 4 * c0);
            gb0[j] = hasB ? *reinterpret_cast<const float4*>(p + 4 * c1)
                          : make_float4(0.f, 0.f, 0.f, 0.f);
        }
        float dv0[KWIN], dv1[KWIN];
#pragma unroll
        for (int j = 0; j < KWIN; ++j) {
            const float* q = wdT + (size_t)(wcellS[j] >> 2) * DOUT;
            dv0[j] = q[tid];
            dv1[j] = q[tid + 512];
        }
#pragma unroll
        for (int j = 0; j < 13; ++j) {
            float d = wd0[j];
            Za[0] = fmaf(d, ga0[j].x, Za[0]); Za[1] = fmaf(d, ga0[j].y, Za[1]);
            Za[2] = fmaf(d, ga0[j].z, Za[2]); Za[3] = fmaf(d, ga0[j].w, Za[3]);
            Zb[0] = fmaf(d, gb0[j].x, Zb[0]); Zb[1] = fmaf(d, gb0[j].y, Zb[1]);
            Zb[2] = fmaf(d, gb0[j].z, Zb[2]); Zb[3] = fmaf(d, gb0[j].w, Zb[3]);
        }
        float4 ga1[12], gb1[12]; float wd1[12];
#pragma unroll
        for (int j = 0; j < 12; ++j) {
            int cell = wcellS[13 + j];
            wd1[j] = wdS[13 + j];
            const float* p = wbT + (size_t)cell * TCELL;
            ga1[j] = *reinterpret_cast<const float4*>(p + 4 * c0);
            gb1[j] = hasB ? *reinterpret_cast<const float4*>(p + 4 * c1)
                          : make_float4(0.f, 0.f, 0.f, 0.f);
        }
        float s0 = breg0, s1 = breg1;
#pragma unroll
        for (int j = 0; j < KWIN; ++j) {
            float yc = wyS[j];
            s0 = fmaf(yc, dv0[j], s0);
            s1 = fmaf(yc, dv1[j], s1);
        }
#pragma unroll
        for (int j = 0; j < 12; ++j) {
            float d = wd1[j];
            Za[0] = fmaf(d, ga1[j].x, Za[0]); Za[1] = fmaf(d, ga1[j].y, Za[1]);
            Za[2] = fmaf(d, ga1[j].z, Za[2]); Za[3] = fmaf(d, ga1[j].w, Za[3]);
            Zb[0] = fmaf(d, gb1[j].x, Zb[0]); Zb[1] = fmaf(d, gb1[j].y, Zb[1]);
            Zb[2] = fmaf(d, gb1[j].z, Zb[2]); Zb[3] = fmaf(d, gb1[j].w, Zb[3]);
        }
        float* orow = out + (size_t)(t * BB + b) * DOUT;
        orow[tid] = s0;
        orow[tid + 512] = s1;
        za0 = zan0;
        za1 = zan1;
        // no trailing barrier: step t+1's LDS writes are to keyS/argnS/dS/ycS,
        // which wave0 finished reading before it arrived at B2(t).
    }
}

// ---------------------------------------------------------------------------
extern "C" void kernel_launch(void* const* d_in, const int* in_sizes, int n_in,
                              void* d_out, int out_size, void* d_ws, size_t ws_size,
                              hipStream_t stream) {
    const float* x   = (const float*)d_in[0];   // [64,128,1024]
    const float* w_a = (const float*)d_in[1];   // [1000,1024]
    const float* w_b = (const float*)d_in[2];   // [4000,4000]
    const float* w_d = (const float*)d_in[3];   // [1024,1000]
    const float* b_d = (const float*)d_in[4];   // [1024]
    float* out = (float*)d_out;                  // [64,128,1024]

    // workspace layout (floats): wbT[16e6] | wdT[1.024e6] | ZA[8.192e6]
    const size_t need_bytes = (size_t)(16000000 + 1024000 + 8192000) * 4;
    if (ws_size < need_bytes) return;  // insufficient scratch: fail loudly
    float* wbT = (float*)d_ws;
    float* wdT = wbT + 16000000;
    float* ZA  = wdT + 1024000;

    transpose_k<<<dim3(125, 125), dim3(32, 8), 0, stream>>>(w_b, wbT, TCELL, TCELL);
    transpose_k<<<dim3(32, 32),  dim3(32, 8), 0, stream>>>(w_d, wdT, DOUT, MCOL);
    za_gemm<<<dim3(64, 8), 256, 0, stream>>>(x, w_a, ZA);
    rsm_kernel<<<128, 512, 0, stream>>>(ZA, wbT, wdT, b_d, out);
}

// Round 4
// 2053.852 us; speedup vs baseline: 1.6962x; 1.6962x over previous
//
#include <hip/hip_runtime.h>
#include <hip/hip_bf16.h>
#include <math.h>

// RSM: M=1000 columns, N=4 cells/col, K=25 winners, T=64, B=128, D_IN=1024, D_OUT=1024
#define MCOL   1000
#define TCELL  4000
#define KWIN   25
#define TT     64
#define BB     128
#define DIN    1024
#define DOUT   1024

// ---------------------------------------------------------------------------
// fp32 transpose: src[R][C] -> dst[C][R]
// ---------------------------------------------------------------------------
__global__ void transpose_k(const float* __restrict__ src, float* __restrict__ dst,
                            int R, int C) {
    __shared__ float tile[32][33];
    int c0 = blockIdx.x * 32, r0 = blockIdx.y * 32;
    int tx = threadIdx.x, ty = threadIdx.y;
#pragma unroll
    for (int q = 0; q < 4; ++q) {
        int r = r0 + ty + q * 8, c = c0 + tx;
        tile[ty + q * 8][tx] = (r < R && c < C) ? src[(size_t)r * C + c] : 0.f;
    }
    __syncthreads();
#pragma unroll
    for (int q = 0; q < 4; ++q) {
        int c = c0 + ty + q * 8, r = r0 + tx;
        if (c < C && r < R) dst[(size_t)c * R + r] = tile[tx][ty + q * 8];
    }
}

// fp32 -> bf16 transpose (decode weights only; no feedback into selection)
__global__ void transpose_bf16_k(const float* __restrict__ src,
                                 __hip_bfloat16* __restrict__ dst, int R, int C) {
    __shared__ float tile[32][33];
    int c0 = blockIdx.x * 32, r0 = blockIdx.y * 32;
    int tx = threadIdx.x, ty = threadIdx.y;
#pragma unroll
    for (int q = 0; q < 4; ++q) {
        int r = r0 + ty + q * 8, c = c0 + tx;
        tile[ty + q * 8][tx] = (r < R && c < C) ? src[(size_t)r * C + c] : 0.f;
    }
    __syncthreads();
#pragma unroll
    for (int q = 0; q < 4; ++q) {
        int c = c0 + ty + q * 8, r = r0 + tx;
        if (c < C && r < R) dst[(size_t)c * R + r] = __float2bfloat16(tile[tx][ty + q * 8]);
    }
}

// ---------------------------------------------------------------------------
// ZA = X[8192,1024] @ w_a^T  -> [8192, 1000]   (fp32 vector GEMM, 128x128x16)
// ---------------------------------------------------------------------------
__launch_bounds__(256, 2)
__global__ void za_gemm(const float* __restrict__ A,   // [8192,1024]
                        const float* __restrict__ Bw,  // [1000,1024]
                        float* __restrict__ C) {       // [8192,1000]
    __shared__ float As[16][132];
    __shared__ float Bs[16][132];
    const int i0 = blockIdx.x * 128;
    const int m0 = blockIdx.y * 128;
    const int tid = threadIdx.x;
    const int tx = tid & 15, ty = tid >> 4;
    float acc[8][8];
#pragma unroll
    for (int a = 0; a < 8; ++a)
#pragma unroll
        for (int b = 0; b < 8; ++b) acc[a][b] = 0.f;

    for (int k0 = 0; k0 < DIN; k0 += 16) {
#pragma unroll
        for (int p = 0; p < 2; ++p) {
            int f = tid + p * 256;
            int row = f >> 2, c4 = (f & 3) * 4;
            float4 v = *reinterpret_cast<const float4*>(
                &A[(size_t)(i0 + row) * DIN + k0 + c4]);
            As[c4 + 0][row] = v.x; As[c4 + 1][row] = v.y;
            As[c4 + 2][row] = v.z; As[c4 + 3][row] = v.w;
            int m = m0 + row;
            float4 w = make_float4(0.f, 0.f, 0.f, 0.f);
            if (m < MCOL)
                w = *reinterpret_cast<const float4*>(&Bw[(size_t)m * DIN + k0 + c4]);
            Bs[c4 + 0][row] = w.x; Bs[c4 + 1][row] = w.y;
            Bs[c4 + 2][row] = w.z; Bs[c4 + 3][row] = w.w;
        }
        __syncthreads();
#pragma unroll
        for (int kk = 0; kk < 16; ++kk) {
            float4 a0 = *reinterpret_cast<const float4*>(&As[kk][ty * 8]);
            float4 a1 = *reinterpret_cast<const float4*>(&As[kk][ty * 8 + 4]);
            float4 b0 = *reinterpret_cast<const float4*>(&Bs[kk][tx * 8]);
            float4 b1 = *reinterpret_cast<const float4*>(&Bs[kk][tx * 8 + 4]);
            float av[8] = {a0.x, a0.y, a0.z, a0.w, a1.x, a1.y, a1.z, a1.w};
            float bv[8] = {b0.x, b0.y, b0.z, b0.w, b1.x, b1.y, b1.z, b1.w};
#pragma unroll
            for (int ii = 0; ii < 8; ++ii)
#pragma unroll
                for (int jj = 0; jj < 8; ++jj)
                    acc[ii][jj] = fmaf(av[ii], bv[jj], acc[ii][jj]);
        }
        __syncthreads();
    }
#pragma unroll
    for (int ii = 0; ii < 8; ++ii) {
        int i = i0 + ty * 8 + ii;
#pragma unroll
        for (int jj = 0; jj < 8; ++jj) {
            int m = m0 + tx * 8 + jj;
            if (m < MCOL) C[(size_t)i * MCOL + m] = acc[ii][jj];
        }
    }
}

__device__ __forceinline__ unsigned long long shflxor64(unsigned long long v, int m) {
    int lo = __shfl_xor((int)(unsigned int)(v & 0xffffffffull), m);
    int hi = __shfl_xor((int)(unsigned int)(v >> 32), m);
    return ((unsigned long long)(unsigned int)hi << 32) | (unsigned int)lo;
}

// ---------------------------------------------------------------------------
// Persistent recurrence: 1 WG (1024 threads, 16 waves) per batch row; thread
// owns column tid (<1000). amdgpu_waves_per_eu(4,4) pins exactly 4 waves/SIMD
// so the allocator uses the full 128-VGPR budget WITHOUT spilling for
// occupancy (rounds 2-3 post-mortem: scheduler spilled 0.7-1.1 GB to scratch).
// Register batches sized to peak ~105 VGPRs; sched_barrier(0) fences stop the
// scheduler hoisting batch-2 loads above batch-1 consumption (reg-peak guard).
// ---------------------------------------------------------------------------
__attribute__((amdgpu_waves_per_eu(4, 4)))
__global__ void __launch_bounds__(1024)
rsm_kernel(const float* __restrict__ ZA,            // [T*B, 1000]
           const float* __restrict__ wbT,           // [4000,4000] = w_b^T (fp32)
           const __hip_bfloat16* __restrict__ wdTb, // [1000,1024] = w_d^T (bf16)
           const float* __restrict__ bd,            // [1024]
           float* __restrict__ out) {               // [T*B, 1024]
    const int b = blockIdx.x;
    const int tid = threadIdx.x;
    const int lane = tid & 63, wid = tid >> 6;      // 16 waves
    const bool isCol = (tid < MCOL);
    const int gcol = isCol ? tid : (MCOL - 1);      // clamp fake lanes' gather addr

    __shared__ unsigned int keyLoS[1024];
    __shared__ unsigned int keyHiS[1024];
    __shared__ float dS[1024];
    __shared__ float ycS[1024];
    __shared__ int   wcellS[KWIN];
    __shared__ float wdS[KWIN];
    __shared__ float wyS[KWIN];

    float Z4[4] = {0,0,0,0}, ph[4] = {0,0,0,0}, ps[4] = {0,0,0,0};
    const float breg = bd[tid];
    float za = isCol ? ZA[(size_t)b * MCOL + tid] : 0.f;

    for (int t = 0; t < TT; ++t) {
        // prefetch next-step feedforward drive (in flight across selection)
        float zan = 0.f;
        if (t + 1 < TT && isCol) zan = ZA[(size_t)((t + 1) * BB + b) * MCOL + tid];

        // ---- phase 1: sigma / pi / per-column max+argmax (first-max) ----
        float sig[4];
        float lam = -INFINITY;
        int an = 0;
#pragma unroll
        for (int n = 0; n < 4; ++n) {
            sig[n] = za + Z4[n];
            float pi = sig[n] * (1.0f - ph[n]);
            if (pi > lam) { lam = pi; an = n; }
        }
        float ysp = tanhf(sig[an]);        // speculative winner activation
        {
            unsigned int ub = __float_as_uint(lam);
            unsigned int u = (ub & 0x80000000u) ? ~ub : (ub | 0x80000000u);
            if (!isCol) u = 0u;            // fakes: below any real key
            // 44-bit key: (u<<12) | ((1023-col)<<2) | argn  == jax order
            keyHiS[tid] = u >> 20;
            keyLoS[tid] = (u << 12) | (unsigned)((1023 - tid) << 2) | (unsigned)an;
            float pd = 0.5f * ps[an];
            dS[tid]  = fmaxf(pd, ysp) - pd;   // psi delta if this col wins
            ycS[tid] = fmaxf(ysp, 0.f);       // y_col if this col wins
        }
        __syncthreads();                                             // B1

        // ---- wave0: exact top-25 extraction (all-static indexing) ----
        if (wid == 0) {
            unsigned long long k[16];
#pragma unroll
            for (int j = 0; j < 16; ++j) {
                int c = lane + 64 * j;
                k[j] = ((unsigned long long)keyHiS[c] << 32) | (unsigned long long)keyLoS[c];
            }
            unsigned long long m = k[0];
#pragma unroll
            for (int j = 1; j < 16; ++j) m = (k[j] > m) ? k[j] : m;
            for (int i = 0; i < KWIN; ++i) {
                unsigned long long g = m;
#pragma unroll
                for (int d = 32; d; d >>= 1) {
                    unsigned long long o = shflxor64(g, d);
                    if (o > g) g = o;
                }
                if (m == g) {              // unique keys -> exactly one lane
                    int c = 1023 - (int)((g >> 2) & 1023ull);
                    int a = (int)(g & 3ull);
                    wcellS[i] = c * 4 + a;
                    wdS[i]    = dS[c];
                    wyS[i]    = ycS[c];
#pragma unroll
                    for (int j = 0; j < 16; ++j) if (k[j] == g) k[j] = 0ull;
                    m = k[0];
#pragma unroll
                    for (int j = 1; j < 16; ++j) m = (k[j] > m) ? k[j] : m;
                }
            }
        }
        __syncthreads();                                             // B2

        // ---- gather batch 0: 13 wbT rows (52 VGPRs in flight) ----
        int won = 0;
        float4 ga0[13];
#pragma unroll
        for (int j = 0; j < 13; ++j) {
            int cell = wcellS[j];
            won |= ((cell >> 2) == tid) ? 1 : 0;
            ga0[j] = *reinterpret_cast<const float4*>(
                wbT + (size_t)cell * TCELL + 4 * gcol);
        }
        int cell1[12];
#pragma unroll
        for (int j = 0; j < 12; ++j) {
            cell1[j] = wcellS[13 + j];
            won |= ((cell1[j] >> 2) == tid) ? 1 : 0;
        }

        // ---- trace updates (registers only; dS used pre-update psi) ----
        float yw = won ? ysp : 0.f;
#pragma unroll
        for (int n = 0; n < 4; ++n) {
            float yn = (n == an) ? yw : 0.f;
            ps[n] = fmaxf(0.5f * ps[n], yn);   // EPS   = 0.5
            ph[n] = fmaxf(0.5f * ph[n], yn);   // GAMMA = 0.5
            Z4[n] *= 0.5f;                     // exact Z decay
        }

        // ---- consume batch 0 ----
#pragma unroll
        for (int j = 0; j < 13; ++j) {
            float d = wdS[j];
            Z4[0] = fmaf(d, ga0[j].x, Z4[0]); Z4[1] = fmaf(d, ga0[j].y, Z4[1]);
            Z4[2] = fmaf(d, ga0[j].z, Z4[2]); Z4[3] = fmaf(d, ga0[j].w, Z4[3]);
        }
        __builtin_amdgcn_sched_barrier(0);   // fence: keep batch-1 below (reg peak)

        // ---- gather batch 1: 12 wbT rows + 25 decode bf16 loads ----
        float4 ga1[12];
#pragma unroll
        for (int j = 0; j < 12; ++j)
            ga1[j] = *reinterpret_cast<const float4*>(
                wbT + (size_t)cell1[j] * TCELL + 4 * gcol);
        float dv[KWIN];
#pragma unroll
        for (int j = 0; j < KWIN; ++j) {
            int col = (j < 13) ? (wcellS[j] >> 2) : (cell1[j - 13] >> 2);
            dv[j] = __bfloat162float(wdTb[(size_t)col * DOUT + tid]);
        }
#pragma unroll
        for (int j = 0; j < 12; ++j) {
            float d = wdS[13 + j];
            Z4[0] = fmaf(d, ga1[j].x, Z4[0]); Z4[1] = fmaf(d, ga1[j].y, Z4[1]);
            Z4[2] = fmaf(d, ga1[j].z, Z4[2]); Z4[3] = fmaf(d, ga1[j].w, Z4[3]);
        }
        float s0 = breg;
#pragma unroll
        for (int j = 0; j < KWIN; ++j) s0 = fmaf(wyS[j], dv[j], s0);

        out[(size_t)(t * BB + b) * DOUT + tid] = s0;
        za = zan;
        // no trailing barrier: t+1's LDS writes (keyS/dS/ycS) precede B1(t+1),
        // and wcellS/wdS/wyS(t) readers all pass B1(t+1) before wave0 rewrites.
    }
}

// ---------------------------------------------------------------------------
extern "C" void kernel_launch(void* const* d_in, const int* in_sizes, int n_in,
                              void* d_out, int out_size, void* d_ws, size_t ws_size,
                              hipStream_t stream) {
    const float* x   = (const float*)d_in[0];   // [64,128,1024]
    const float* w_a = (const float*)d_in[1];   // [1000,1024]
    const float* w_b = (const float*)d_in[2];   // [4000,4000]
    const float* w_d = (const float*)d_in[3];   // [1024,1000]
    const float* b_d = (const float*)d_in[4];   // [1024]
    float* out = (float*)d_out;                  // [64,128,1024]

    // workspace: wbT fp32[16e6] | ZA fp32[8.192e6] | wdTb bf16[1.024e6]
    const size_t need_bytes = (size_t)(16000000 + 8192000) * 4 + 1024000 * 2;
    if (ws_size < need_bytes) return;
    float* wbT = (float*)d_ws;
    float* ZA  = wbT + 16000000;
    __hip_bfloat16* wdTb = (__hip_bfloat16*)(ZA + 8192000);

    transpose_k<<<dim3(125, 125), dim3(32, 8), 0, stream>>>(w_b, wbT, TCELL, TCELL);
    transpose_bf16_k<<<dim3(32, 32), dim3(32, 8), 0, stream>>>(w_d, wdTb, DOUT, MCOL);
    za_gemm<<<dim3(64, 8), 256, 0, stream>>>(x, w_a, ZA);
    rsm_kernel<<<128, 1024, 0, stream>>>(ZA, wbT, wdTb, b_d, out);
}